// Round 10
// baseline (60.636 us; speedup 1.0000x reference)
//
#include <hip/hip_runtime.h>
#include <math.h>

#define NN 4096
#define FF 128
#define DD 64
#define HH 4
#define NC 256  // HH*DD output columns

typedef _Float16 f16x8 __attribute__((ext_vector_type(8)));
typedef _Float16 f16x4 __attribute__((ext_vector_type(4)));
typedef _Float16 f16x2 __attribute__((ext_vector_type(2)));
typedef float    f32x4 __attribute__((ext_vector_type(4)));

// ---------------------------------------------------------------------------
// Kernel 0: adjacency -> plane-packed bitmask, fully coalesced.
// Lane i reads int4 at +i*16 (1KB dense per instruction); 4 ballots pack 256
// elements into 2 uint4 in PLANE order:
//   adjp[g*2+half].c bit b  <->  adj element g*256 + half*128 + b*4 + c
// (half = 0 for lanes 0..31, 1 for lanes 32..63).
// ---------------------------------------------------------------------------
__global__ __launch_bounds__(256) void adjbits_kernel(
    const int* __restrict__ adj, uint4* __restrict__ adjp)
{
    const int wid  = blockIdx.x * 4 + (threadIdx.x >> 6);  // 8192 waves
    const int lane = threadIdx.x & 63;
    const int4* __restrict__ base = (const int4*)adj;
    #pragma unroll
    for (int i = 0; i < 8; ++i) {
        const int g = wid * 8 + i;                          // group of 256 elems
        const int4 v = base[(size_t)g * 64 + lane];
        unsigned long long b0 = __ballot(v.x != 0);
        unsigned long long b1 = __ballot(v.y != 0);
        unsigned long long b2 = __ballot(v.z != 0);
        unsigned long long b3 = __ballot(v.w != 0);
        if (lane == 0) {
            adjp[g * 2] = (uint4){(unsigned)b0, (unsigned)b1,
                                  (unsigned)b2, (unsigned)b3};
            adjp[g * 2 + 1] = (uint4){(unsigned)(b0 >> 32), (unsigned)(b1 >> 32),
                                      (unsigned)(b2 >> 32), (unsigned)(b3 >> 32)};
        }
    }
}

// ---------------------------------------------------------------------------
// Kernel 1: h = features @ W[h] via f16 LDS staging + v_dot2_f32_f16
// (half the LDS traffic of f32; 33.7KB LDS -> 4 blocks/CU). Emits Bpack
// (f16 MFMA-B-fragment-ordered chunks) and f16 exp tables Es,Fs,En,Fn.
// ---------------------------------------------------------------------------
__global__ __launch_bounds__(256) void prep_kernel(
    const float* __restrict__ feats, const float* __restrict__ W,
    const float* __restrict__ ak, _Float16* __restrict__ Bpack,
    _Float16* __restrict__ Es, _Float16* __restrict__ Fs,
    _Float16* __restrict__ En, _Float16* __restrict__ Fn)
{
    __shared__ _Float16 Wth[64 * 136];   // [d][f] f16, stride 136 (16B-aligned rows)
    __shared__ _Float16 fth[32 * 128];   // [r][f] f16
    __shared__ float    hlds[32 * 65];   // h tile f32 (for exp tables + Bpack)
    const int t  = threadIdx.x;
    const int h  = blockIdx.y;
    const int n0 = blockIdx.x * 32;

    {
        const float* Wh = W + h * (FF * DD);
        #pragma unroll
        for (int j = 0; j < 8; ++j) {
            int idx = j * 256 + t;
            int f   = idx >> 4;
            int d4  = idx & 15;
            float4 v = ((const float4*)Wh)[idx];
            Wth[(d4 * 4 + 0) * 136 + f] = (_Float16)v.x;
            Wth[(d4 * 4 + 1) * 136 + f] = (_Float16)v.y;
            Wth[(d4 * 4 + 2) * 136 + f] = (_Float16)v.z;
            Wth[(d4 * 4 + 3) * 136 + f] = (_Float16)v.w;
        }
        #pragma unroll
        for (int j = 0; j < 4; ++j) {
            int idx = j * 256 + t;
            int r = idx >> 5, f4 = idx & 31;
            float4 v = ((const float4*)feats)[(size_t)(n0 + r) * 32 + f4];
            f16x4 hv = {(_Float16)v.x, (_Float16)v.y, (_Float16)v.z, (_Float16)v.w};
            *(f16x4*)&fth[r * 128 + f4 * 4] = hv;
        }
    }
    __syncthreads();

    const int d   = t & 63;
    const int wid = t >> 6;
    float acc[8];
    #pragma unroll
    for (int j = 0; j < 8; ++j) acc[j] = 0.f;

    for (int f8 = 0; f8 < 16; ++f8) {
        const f16x8 w8 = *(const f16x8*)&Wth[d * 136 + f8 * 8];
        const f16x2 w0 = __builtin_shufflevector(w8, w8, 0, 1);
        const f16x2 w1 = __builtin_shufflevector(w8, w8, 2, 3);
        const f16x2 w2 = __builtin_shufflevector(w8, w8, 4, 5);
        const f16x2 w3 = __builtin_shufflevector(w8, w8, 6, 7);
        #pragma unroll
        for (int j = 0; j < 8; ++j) {
            const int r = wid + 4 * j;
            const f16x8 fv = *(const f16x8*)&fth[r * 128 + f8 * 8];
            acc[j] = __builtin_amdgcn_fdot2(w0, __builtin_shufflevector(fv, fv, 0, 1), acc[j], false);
            acc[j] = __builtin_amdgcn_fdot2(w1, __builtin_shufflevector(fv, fv, 2, 3), acc[j], false);
            acc[j] = __builtin_amdgcn_fdot2(w2, __builtin_shufflevector(fv, fv, 4, 5), acc[j], false);
            acc[j] = __builtin_amdgcn_fdot2(w3, __builtin_shufflevector(fv, fv, 6, 7), acc[j], false);
        }
    }

    const float aks = ak[h * 128 + d];
    const float akn = ak[h * 128 + 64 + d];
    #pragma unroll
    for (int j = 0; j < 8; ++j) {
        const int r = wid + 4 * j;
        const float hv = acc[j];
        hlds[r * 65 + d] = hv;
        float v1 = hv * aks;
        float v2 = hv * akn;
        #pragma unroll
        for (int m = 32; m >= 1; m >>= 1) {
            v1 += __shfl_xor(v1, m, 64);
            v2 += __shfl_xor(v2, m, 64);
        }
        if (d == 0) {
            Es[h * NN + n0 + r] = (_Float16)__expf(v1);
            Fs[h * NN + n0 + r] = (_Float16)__expf(0.2f * v1);
            En[h * NN + n0 + r] = (_Float16)__expf(v2);
            Fn[h * NN + n0 + r] = (_Float16)__expf(0.2f * v2);
        }
    }
    __syncthreads();

    const int cb = t >> 6;
    const int l  = t & 63;
    const int lr = l & 15;
    const int kg = l >> 4;
    f16x8 v;
    #pragma unroll
    for (int j = 0; j < 8; ++j)
        v[j] = (_Float16)hlds[(kg * 8 + j) * 65 + cb * 16 + lr];
    *(f16x8*)(Bpack + ((size_t)(h * 128 + blockIdx.x)) * 2048 + (cb * 64 + l) * 8) = v;
}

// ---------------------------------------------------------------------------
// Kernel 2: MFMA attention (R9 form, mask path adapted to plane layout).
// Per 4-chunk block cqp: one uint4 per row holds planes {P0,P1,P2,P3};
// chunk ci, lane-group kg: q = ci*8+kg*2; element j=2p(,+1) maps to plane
// {0,1}/{2,3} at bit q/(q+1). Everything else (rotation, LDS double-buffer,
// B 2-ahead, tables 1-ahead) unchanged.
// ---------------------------------------------------------------------------
__global__ __launch_bounds__(256, 4) void attn_kernel(
    const uint4* __restrict__ adjp, const _Float16* __restrict__ Bpack,
    const _Float16* __restrict__ Es, const _Float16* __restrict__ Fs,
    const _Float16* __restrict__ En, const _Float16* __restrict__ Fn,
    float* __restrict__ pacc, float* __restrict__ pden, int ksplit)
{
    __shared__ _Float16 Blds[2][2048];   // 2 x 4KB double buffer

    const int t  = threadIdx.x;
    const int w  = t >> 6;
    const int l  = t & 63;
    const int lr = l & 15;
    const int kg = l >> 4;
    const int h  = blockIdx.y;
    const int s  = blockIdx.z;
    const int n0 = blockIdx.x * 128 + w * 32;

    const int mstart = s * ksplit;
    const int nchunk = ksplit >> 5;
    const int ncq    = nchunk >> 2;
    const int coff   = blockIdx.x & (ncq - 1);
    const int wqb    = mstart >> 7;        // halfgroup (uint4) base, 32 per row

#define PC(c) (((((c) >> 2) + coff) & (ncq - 1)) * 4 + ((c) & 3))

    const _Float16 es0 = Es[h * NN + n0 + lr],      fs0 = Fs[h * NN + n0 + lr];
    const _Float16 es1 = Es[h * NN + n0 + 16 + lr], fs1 = Fs[h * NN + n0 + 16 + lr];
    const f16x2 es20 = {es0, es0}, fs20 = {fs0, fs0};
    const f16x2 es21 = {es1, es1}, fs21 = {fs1, fs1};

    const _Float16* __restrict__ EnB = En + (size_t)h * NN;
    const _Float16* __restrict__ FnB = Fn + (size_t)h * NN;
    const uint4* __restrict__ adjpR0 = adjp + (size_t)(n0 + lr) * 32;
    const uint4* __restrict__ adjpR1 = adjp + (size_t)(n0 + 16 + lr) * 32;

    const _Float16* __restrict__ bp =
        Bpack + ((size_t)(h * 128) + (mstart >> 5)) * 2048 + t * 8;

    f32x4 acc[2][4] = {};
    f32x4 dacc[2]   = {};
    f16x8 ones;
    #pragma unroll
    for (int j = 0; j < 8; ++j) ones[j] = (_Float16)1.0f;

    union U8 { f16x8 v; unsigned int u[4]; };

    // ---- prologue ----
    uint4 sreg = *(const uint4*)(bp + (size_t)PC(0) * 2048);
    *(uint4*)&Blds[0][t * 8] = sreg;
    sreg = *(const uint4*)(bp + (size_t)PC(1) * 2048);
    uint4 enqc = *(const uint4*)(EnB + mstart + PC(0) * 32 + kg * 8);
    uint4 fnqc = *(const uint4*)(FnB + mstart + PC(0) * 32 + kg * 8);
    __syncthreads();

    for (int cq = 0; cq < ncq; ++cq) {
        const int cqp = (cq + coff) & (ncq - 1);
        const uint4 mk0 = adjpR0[wqb + cqp];   // planes P0..P3 for 4 chunks, row0
        const uint4 mk1 = adjpR1[wqb + cqp];   // row1

        #pragma unroll
        for (int ci = 0; ci < 4; ++ci) {
            const int c = cq * 4 + ci;

            uint4 nreg;
            {
                const int cn = (c + 2 < nchunk) ? c + 2 : c;
                nreg = *(const uint4*)(bp + (size_t)PC(cn) * 2048);
            }
            if (c + 1 < nchunk)
                *(uint4*)&Blds[(c + 1) & 1][t * 8] = sreg;
            uint4 enq_n, fnq_n;
            {
                const int cn = (c + 1 < nchunk) ? c + 1 : c;
                enq_n = *(const uint4*)(EnB + mstart + PC(cn) * 32 + kg * 8);
                fnq_n = *(const uint4*)(FnB + mstart + PC(cn) * 32 + kg * 8);
            }

            // ---- plane-layout mask extraction ----
            const int q = ci * 8 + kg * 2;
            const unsigned int t0 = mk0.x >> q, t1 = mk0.y >> q;
            const unsigned int t2 = mk0.z >> q, t3 = mk0.w >> q;
            const unsigned int u0 = mk1.x >> q, u1 = mk1.y >> q;
            const unsigned int u2 = mk1.z >> q, u3 = mk1.w >> q;
            unsigned int mmA[4], mmB[4];
            mmA[0] = ((t0 & 1u) ? 0x0000FFFFu : 0u) | ((t1 & 1u) ? 0xFFFF0000u : 0u);
            mmA[1] = ((t2 & 1u) ? 0x0000FFFFu : 0u) | ((t3 & 1u) ? 0xFFFF0000u : 0u);
            mmA[2] = (((t0 >> 1) & 1u) ? 0x0000FFFFu : 0u) | (((t1 >> 1) & 1u) ? 0xFFFF0000u : 0u);
            mmA[3] = (((t2 >> 1) & 1u) ? 0x0000FFFFu : 0u) | (((t3 >> 1) & 1u) ? 0xFFFF0000u : 0u);
            mmB[0] = ((u0 & 1u) ? 0x0000FFFFu : 0u) | ((u1 & 1u) ? 0xFFFF0000u : 0u);
            mmB[1] = ((u2 & 1u) ? 0x0000FFFFu : 0u) | ((u3 & 1u) ? 0xFFFF0000u : 0u);
            mmB[2] = (((u0 >> 1) & 1u) ? 0x0000FFFFu : 0u) | (((u1 >> 1) & 1u) ? 0xFFFF0000u : 0u);
            mmB[3] = (((u2 >> 1) & 1u) ? 0x0000FFFFu : 0u) | (((u3 >> 1) & 1u) ? 0xFFFF0000u : 0u);

            U8 A0, A1;
            #pragma unroll
            for (int p = 0; p < 4; ++p) {
                const unsigned int eu = p == 0 ? enqc.x : p == 1 ? enqc.y : p == 2 ? enqc.z : enqc.w;
                const unsigned int fu = p == 0 ? fnqc.x : p == 1 ? fnqc.y : p == 2 ? fnqc.z : fnqc.w;
                const f16x2 en2 = __builtin_bit_cast(f16x2, eu);
                const f16x2 fn2 = __builtin_bit_cast(f16x2, fu);
                const f16x2 v0 = __builtin_elementwise_max(es20 * en2, fs20 * fn2);
                const f16x2 v1 = __builtin_elementwise_max(es21 * en2, fs21 * fn2);
                A0.u[p] = __builtin_bit_cast(unsigned int, v0) & mmA[p];
                A1.u[p] = __builtin_bit_cast(unsigned int, v1) & mmB[p];
            }

            __builtin_amdgcn_s_setprio(1);
            #pragma unroll
            for (int cb = 0; cb < 4; ++cb) {
                const f16x8 Bf = *(const f16x8*)&Blds[c & 1][(cb * 64 + l) * 8];
                acc[0][cb] = __builtin_amdgcn_mfma_f32_16x16x32_f16(A0.v, Bf, acc[0][cb], 0, 0, 0);
                acc[1][cb] = __builtin_amdgcn_mfma_f32_16x16x32_f16(A1.v, Bf, acc[1][cb], 0, 0, 0);
            }
            dacc[0] = __builtin_amdgcn_mfma_f32_16x16x32_f16(A0.v, ones, dacc[0], 0, 0, 0);
            dacc[1] = __builtin_amdgcn_mfma_f32_16x16x32_f16(A1.v, ones, dacc[1], 0, 0, 0);
            __builtin_amdgcn_s_setprio(0);

            __syncthreads();
            sreg = nreg;
            enqc = enq_n;
            fnqc = fnq_n;
        }
    }
#undef PC

    #pragma unroll
    for (int rb = 0; rb < 2; ++rb) {
        #pragma unroll
        for (int r = 0; r < 4; ++r) {
            const int row = n0 + rb * 16 + kg * 4 + r;
            #pragma unroll
            for (int cb = 0; cb < 4; ++cb)
                pacc[((size_t)(s * NN + row)) * NC + h * 64 + cb * 16 + lr] = acc[rb][cb][r];
            if (lr == 0)
                pden[(s * NN + row) * 4 + h] = dacc[rb][r];
        }
    }
}

// ---------------------------------------------------------------------------
// Kernel 3: reduce splits, normalize, ReLU. float4 per thread, 4 rows/block.
// ---------------------------------------------------------------------------
__global__ __launch_bounds__(256) void finalize_kernel(
    const float* __restrict__ pacc, const float* __restrict__ pden,
    float* __restrict__ out, int nsplit)
{
    const int t = threadIdx.x;
    const int n = blockIdx.x * 4 + (t >> 6);
    const int q = t & 63;
    const int h = q >> 4;

    f32x4 a = {0.f, 0.f, 0.f, 0.f};
    float d = 0.f;
    for (int s = 0; s < nsplit; ++s) {
        a += *(const f32x4*)&pacc[((size_t)(s * NN + n)) * NC + q * 4];
        d += pden[(s * NN + n) * 4 + h];
    }
    f32x4 o;
    const float inv = (d > 0.f) ? 1.0f / d : 0.f;
    #pragma unroll
    for (int i = 0; i < 4; ++i) {
        const float v = a[i] * inv;
        o[i] = v > 0.f ? v : 0.f;
    }
    *(f32x4*)&out[(size_t)n * NC + q * 4] = o;
}

// ---------------------------------------------------------------------------
extern "C" void kernel_launch(void* const* d_in, const int* in_sizes, int n_in,
                              void* d_out, int out_size, void* d_ws, size_t ws_size,
                              hipStream_t stream)
{
    const int*   adj   = (const int*)d_in[0];
    const float* feats = (const float*)d_in[1];
    const float* W     = (const float*)d_in[2];
    const float* ak    = (const float*)d_in[3];
    float*       out   = (float*)d_out;

    char* ws = (char*)d_ws;
    uint4*        adjp  = (uint4*)ws;                                 // 2 MB
    _Float16*     Bpack = (_Float16*)(ws + (2ull << 20));             // 2 MB
    _Float16*     Es    = (_Float16*)(ws + (4ull << 20));             // 32 KB
    _Float16*     Fs    = (_Float16*)(ws + (4ull << 20) + (1 << 16)); // 32 KB
    _Float16*     En    = (_Float16*)(ws + (4ull << 20) + (2 << 16)); // 32 KB
    _Float16*     Fn    = (_Float16*)(ws + (4ull << 20) + (3 << 16)); // 32 KB
    float*        pden  = (float*)(ws + (4ull << 20) + (4 << 16));    // <=512 KB
    float*        pacc  = (float*)(ws + (5ull << 20));                // nsplit*4 MB

    int nsplit = 8;
    while (nsplit > 1 && ws_size < (5ull << 20) + (size_t)nsplit * (4ull << 20))
        nsplit >>= 1;
    const int ksplit = NN / nsplit;

    adjbits_kernel<<<2048, 256, 0, stream>>>(adj, adjp);
    prep_kernel<<<dim3(128, 4), 256, 0, stream>>>(feats, W, ak, Bpack, Es, Fs, En, Fn);
    attn_kernel<<<dim3(32, 4, nsplit), 256, 0, stream>>>(adjp, Bpack, Es, Fs, En, Fn,
                                                         pacc, pden, ksplit);
    finalize_kernel<<<1024, 256, 0, stream>>>(pacc, pden, out, nsplit);
}

// Round 12
// 57.139 us; speedup vs baseline: 1.0612x; 1.0612x over previous
//
#include <hip/hip_runtime.h>
#include <math.h>

#define NN 4096
#define FF 128
#define DD 64
#define HH 4
#define NC 256  // HH*DD output columns

typedef _Float16 f16x8 __attribute__((ext_vector_type(8)));
typedef _Float16 f16x4 __attribute__((ext_vector_type(4)));
typedef _Float16 f16x2 __attribute__((ext_vector_type(2)));
typedef float    f32x4 __attribute__((ext_vector_type(4)));

// ---------------------------------------------------------------------------
// Kernel 1: h = features @ W[h] via f16 LDS staging + v_dot2_f32_f16.
// Emits Bpack (f16 MFMA-B-fragment-ordered chunks: Bpack[h][chunk][cb][lane][8],
// 4KB contiguous per 64d x 32m chunk) and f16 exp tables Es,Fs,En,Fn ([h][n]).
// ---------------------------------------------------------------------------
__global__ __launch_bounds__(256) void prep_kernel(
    const float* __restrict__ feats, const float* __restrict__ W,
    const float* __restrict__ ak, _Float16* __restrict__ Bpack,
    _Float16* __restrict__ Es, _Float16* __restrict__ Fs,
    _Float16* __restrict__ En, _Float16* __restrict__ Fn)
{
    __shared__ _Float16 Wth[64 * 136];
    __shared__ _Float16 fth[32 * 128];
    __shared__ float    hlds[32 * 65];
    const int t  = threadIdx.x;
    const int h  = blockIdx.y;
    const int n0 = blockIdx.x * 32;

    {
        const float* Wh = W + h * (FF * DD);
        #pragma unroll
        for (int j = 0; j < 8; ++j) {
            int idx = j * 256 + t;
            int f   = idx >> 4;
            int d4  = idx & 15;
            float4 v = ((const float4*)Wh)[idx];
            Wth[(d4 * 4 + 0) * 136 + f] = (_Float16)v.x;
            Wth[(d4 * 4 + 1) * 136 + f] = (_Float16)v.y;
            Wth[(d4 * 4 + 2) * 136 + f] = (_Float16)v.z;
            Wth[(d4 * 4 + 3) * 136 + f] = (_Float16)v.w;
        }
        #pragma unroll
        for (int j = 0; j < 4; ++j) {
            int idx = j * 256 + t;
            int r = idx >> 5, f4 = idx & 31;
            float4 v = ((const float4*)feats)[(size_t)(n0 + r) * 32 + f4];
            f16x4 hv = {(_Float16)v.x, (_Float16)v.y, (_Float16)v.z, (_Float16)v.w};
            *(f16x4*)&fth[r * 128 + f4 * 4] = hv;
        }
    }
    __syncthreads();

    const int d   = t & 63;
    const int wid = t >> 6;
    float acc[8];
    #pragma unroll
    for (int j = 0; j < 8; ++j) acc[j] = 0.f;

    union UW { f16x8 v; unsigned int u[4]; };
    for (int f8 = 0; f8 < 16; ++f8) {
        UW w8; w8.v = *(const f16x8*)&Wth[d * 136 + f8 * 8];
        #pragma unroll
        for (int j = 0; j < 8; ++j) {
            const int r = wid + 4 * j;
            UW fv; fv.v = *(const f16x8*)&fth[r * 128 + f8 * 8];
            #pragma unroll
            for (int p = 0; p < 4; ++p)
                acc[j] = __builtin_amdgcn_fdot2(
                    __builtin_bit_cast(f16x2, w8.u[p]),
                    __builtin_bit_cast(f16x2, fv.u[p]), acc[j], false);
        }
    }

    const float aks = ak[h * 128 + d];
    const float akn = ak[h * 128 + 64 + d];
    #pragma unroll
    for (int j = 0; j < 8; ++j) {
        const int r = wid + 4 * j;
        const float hv = acc[j];
        hlds[r * 65 + d] = hv;
        float v1 = hv * aks;
        float v2 = hv * akn;
        #pragma unroll
        for (int m = 32; m >= 1; m >>= 1) {
            v1 += __shfl_xor(v1, m, 64);
            v2 += __shfl_xor(v2, m, 64);
        }
        if (d == 0) {
            Es[h * NN + n0 + r] = (_Float16)__expf(v1);
            Fs[h * NN + n0 + r] = (_Float16)__expf(0.2f * v1);
            En[h * NN + n0 + r] = (_Float16)__expf(v2);
            Fn[h * NN + n0 + r] = (_Float16)__expf(0.2f * v2);
        }
    }
    __syncthreads();

    const int cb = t >> 6;
    const int l  = t & 63;
    const int lr = l & 15;
    const int kg = l >> 4;
    f16x8 v;
    #pragma unroll
    for (int j = 0; j < 8; ++j)
        v[j] = (_Float16)hlds[(kg * 8 + j) * 65 + cb * 16 + lr];
    *(f16x8*)(Bpack + ((size_t)(h * 128 + blockIdx.x)) * 2048 + (cb * 64 + l) * 8) = v;
}

// ---------------------------------------------------------------------------
// Kernel 2: fused MFMA attention. Block = 4 waves = 4 HEADS sharing rows
// n0..n0+31 (mask is head-independent -> adj read EXACTLY once, fused).
// Per chunk: block stages 32x32 raw adj ints (coalesced int4) -> f16 0/1 in
// LDS (16B-granule XOR swizzle); pair-buffered 2 chunks deep (adj prefetched
// 4 chunks ahead to cover HBM latency; 1 barrier / 2 chunks). B-frags are
// dense per-wave global loads from L2-resident Bpack with chunk rotation.
// A = max(Es*En, Fs*Fn) * adj01 (packed f16). mfma_f32_16x16x32_f16;
// C layout col=lane&15, row=(lane>>4)*4+reg [verified].
// ---------------------------------------------------------------------------
__global__ __launch_bounds__(256, 4) void attn_kernel(
    const int* __restrict__ adj, const _Float16* __restrict__ Bpack,
    const _Float16* __restrict__ Es, const _Float16* __restrict__ Fs,
    const _Float16* __restrict__ En, const _Float16* __restrict__ Fn,
    float* __restrict__ pacc, float* __restrict__ pden, int ksplit)
{
    __shared__ _Float16 adjh[2][2][1024];   // [pairbuf][sub][32r x 32m] = 8KB

    const int t  = threadIdx.x;
    const int h  = t >> 6;                  // wave = head
    const int l  = t & 63;
    const int lr = l & 15;
    const int kg = l >> 4;
    const int n0 = blockIdx.x * 32;
    const int s  = blockIdx.y;

    const int mstart = s * ksplit;
    const int nch    = ksplit >> 5;
    const int coff   = blockIdx.x & (nch - 1);
#define PCH(c) ((((c) + coff) & (nch - 1)))
#define CLC(c) ((c) < nch ? (c) : nch - 1)

    const _Float16 es0 = Es[h * NN + n0 + lr],      fs0 = Fs[h * NN + n0 + lr];
    const _Float16 es1 = Es[h * NN + n0 + 16 + lr], fs1 = Fs[h * NN + n0 + 16 + lr];
    const f16x2 es20 = {es0, es0}, fs20 = {fs0, fs0};
    const f16x2 es21 = {es1, es1}, fs21 = {fs1, fs1};

    const _Float16* __restrict__ EnB = En + (size_t)h * NN + mstart + kg * 8;
    const _Float16* __restrict__ FnB = Fn + (size_t)h * NN + mstart + kg * 8;
    const _Float16* __restrict__ bhead =
        Bpack + ((size_t)(h * 128) + (mstart >> 5)) * 2048 + l * 8;

    // staging: thread t -> row sr, quad mq (4 ints); swizzled LDS f16 offset
    const int sr = t >> 3;
    const int mq = t & 7;
    const int swoff = sr * 32 + (((mq >> 1) ^ (sr & 3)) << 3) + (mq & 1) * 4;
    const int* __restrict__ adjRow = adj + (size_t)(n0 + sr) * NN + mstart;

    // A-side LDS read offsets (granule swizzle; (lr+16)&3 == lr&3)
    const int perm = kg ^ (lr & 3);
    const int ro0  = lr * 32 + perm * 8;
    const int ro1  = (lr + 16) * 32 + perm * 8;

    f32x4 acc[2][4] = {};
    f32x4 dacc[2]   = {};
    f16x8 ones;
    #pragma unroll
    for (int j = 0; j < 8; ++j) ones[j] = (_Float16)1.0f;

    union U8 { f16x8 v; unsigned int u[4]; };

#define LDADJ(DST, C) do {                                                    \
        DST = ((const int4*)(adjRow + PCH(CLC(C)) * 32))[mq];                 \
    } while (0)
#define STADJ(PB, SUB, SRC) do {                                              \
        f16x4 _hv = {(_Float16)(SRC.x != 0), (_Float16)(SRC.y != 0),          \
                     (_Float16)(SRC.z != 0), (_Float16)(SRC.w != 0)};         \
        *(f16x4*)&adjh[PB][SUB][swoff] = _hv;                                 \
    } while (0)
#define LOADB(DST, C) do {                                                    \
        const _Float16* _b = bhead + (size_t)PCH(CLC(C)) * 2048;              \
        _Pragma("unroll")                                                     \
        for (int _cb = 0; _cb < 4; ++_cb)                                     \
            DST[_cb] = *(const f16x8*)(_b + _cb * 512);                       \
    } while (0)
#define LOADT(EQ, FQ, C) do {                                                 \
        EQ = *(const uint4*)(EnB + PCH(CLC(C)) * 32);                         \
        FQ = *(const uint4*)(FnB + PCH(CLC(C)) * 32);                         \
    } while (0)

#define CHUNK(C, PB, SUB, BCUR, BNXT, EQC, FQC, EQN, FQN) do {                \
        LOADB(BNXT, (C) + 1);                                                 \
        LOADT(EQN, FQN, (C) + 1);                                             \
        U8 AM0, AM1;                                                          \
        AM0.v = *(const f16x8*)&adjh[PB][SUB][ro0];                           \
        AM1.v = *(const f16x8*)&adjh[PB][SUB][ro1];                           \
        U8 A0, A1;                                                            \
        _Pragma("unroll")                                                     \
        for (int p = 0; p < 4; ++p) {                                         \
            const unsigned int eu = p == 0 ? EQC.x : p == 1 ? EQC.y : p == 2 ? EQC.z : EQC.w; \
            const unsigned int fu = p == 0 ? FQC.x : p == 1 ? FQC.y : p == 2 ? FQC.z : FQC.w; \
            const f16x2 en2 = __builtin_bit_cast(f16x2, eu);                  \
            const f16x2 fn2 = __builtin_bit_cast(f16x2, fu);                  \
            const f16x2 a20 = __builtin_bit_cast(f16x2, AM0.u[p]);            \
            const f16x2 a21 = __builtin_bit_cast(f16x2, AM1.u[p]);            \
            const f16x2 v0 = __builtin_elementwise_max(es20 * en2, fs20 * fn2) * a20; \
            const f16x2 v1 = __builtin_elementwise_max(es21 * en2, fs21 * fn2) * a21; \
            A0.u[p] = __builtin_bit_cast(unsigned int, v0);                   \
            A1.u[p] = __builtin_bit_cast(unsigned int, v1);                   \
        }                                                                     \
        __builtin_amdgcn_s_setprio(1);                                        \
        _Pragma("unroll")                                                     \
        for (int _cb = 0; _cb < 4; ++_cb) {                                   \
            acc[0][_cb] = __builtin_amdgcn_mfma_f32_16x16x32_f16(A0.v, BCUR[_cb], acc[0][_cb], 0, 0, 0); \
            acc[1][_cb] = __builtin_amdgcn_mfma_f32_16x16x32_f16(A1.v, BCUR[_cb], acc[1][_cb], 0, 0, 0); \
        }                                                                     \
        dacc[0] = __builtin_amdgcn_mfma_f32_16x16x32_f16(A0.v, ones, dacc[0], 0, 0, 0); \
        dacc[1] = __builtin_amdgcn_mfma_f32_16x16x32_f16(A1.v, ones, dacc[1], 0, 0, 0); \
        __builtin_amdgcn_s_setprio(0);                                        \
    } while (0)

    f16x8 B_0[4], B_1[4];
    uint4 eq0, fq0, eq1, fq1;
    int4  aA, aB;

    // ---- prologue: pair 0 -> buf0; regs <- pair 1; B/tables for chunk 0 ----
    LDADJ(aA, 0);
    LDADJ(aB, 1);
    STADJ(0, 0, aA);
    STADJ(0, 1, aB);
    LDADJ(aA, 2);
    LDADJ(aB, 3);
    LOADB(B_0, 0);
    LOADT(eq0, fq0, 0);
    __syncthreads();

    const int npair = nch >> 1;
    for (int k = 0; k < npair; ++k) {
        const int nb = (k + 1) & 1;
        const int pb = k & 1;
        // stage pair k+1 (regs loaded at pair k-1), prefetch pair k+2
        STADJ(nb, 0, aA);
        STADJ(nb, 1, aB);
        LDADJ(aA, 2 * k + 4);
        LDADJ(aB, 2 * k + 5);

        CHUNK(2 * k,     pb, 0, B_0, B_1, eq0, fq0, eq1, fq1);
        CHUNK(2 * k + 1, pb, 1, B_1, B_0, eq1, fq1, eq0, fq0);

        __syncthreads();
    }
#undef CHUNK
#undef LOADT
#undef LOADB
#undef STADJ
#undef LDADJ
#undef CLC
#undef PCH

    #pragma unroll
    for (int rb = 0; rb < 2; ++rb) {
        #pragma unroll
        for (int r = 0; r < 4; ++r) {
            const int row = n0 + rb * 16 + kg * 4 + r;
            #pragma unroll
            for (int cb = 0; cb < 4; ++cb)
                pacc[((size_t)(s * NN + row)) * NC + h * 64 + cb * 16 + lr] = acc[rb][cb][r];
            if (lr == 0)
                pden[(s * NN + row) * 4 + h] = dacc[rb][r];
        }
    }
}

// ---------------------------------------------------------------------------
// Kernel 3: reduce splits, normalize, ReLU. float4 per thread, 4 rows/block.
// ---------------------------------------------------------------------------
__global__ __launch_bounds__(256) void finalize_kernel(
    const float* __restrict__ pacc, const float* __restrict__ pden,
    float* __restrict__ out, int nsplit)
{
    const int t = threadIdx.x;
    const int n = blockIdx.x * 4 + (t >> 6);
    const int q = t & 63;
    const int h = q >> 4;

    f32x4 a = {0.f, 0.f, 0.f, 0.f};
    float d = 0.f;
    for (int s = 0; s < nsplit; ++s) {
        a += *(const f32x4*)&pacc[((size_t)(s * NN + n)) * NC + q * 4];
        d += pden[(s * NN + n) * 4 + h];
    }
    f32x4 o;
    const float inv = (d > 0.f) ? 1.0f / d : 0.f;
    #pragma unroll
    for (int i = 0; i < 4; ++i) {
        const float v = a[i] * inv;
        o[i] = v > 0.f ? v : 0.f;
    }
    *(f32x4*)&out[(size_t)n * NC + q * 4] = o;
}

// ---------------------------------------------------------------------------
extern "C" void kernel_launch(void* const* d_in, const int* in_sizes, int n_in,
                              void* d_out, int out_size, void* d_ws, size_t ws_size,
                              hipStream_t stream)
{
    const int*   adj   = (const int*)d_in[0];
    const float* feats = (const float*)d_in[1];
    const float* W     = (const float*)d_in[2];
    const float* ak    = (const float*)d_in[3];
    float*       out   = (float*)d_out;

    char* ws = (char*)d_ws;
    _Float16* Bpack = (_Float16*)ws;                                  // 2 MB
    _Float16* Es    = (_Float16*)(ws + (2ull << 20));                 // 32 KB
    _Float16* Fs    = (_Float16*)(ws + (2ull << 20) + (1 << 15));     // 32 KB
    _Float16* En    = (_Float16*)(ws + (2ull << 20) + (2 << 15));     // 32 KB
    _Float16* Fn    = (_Float16*)(ws + (2ull << 20) + (3 << 15));     // 32 KB
    float*    pden  = (float*)(ws + (2ull << 20) + (4 << 15));        // <=512 KB
    float*    pacc  = (float*)(ws + (3ull << 20));                    // nsplit*4 MB

    int nsplit = 8;
    while (nsplit > 1 && ws_size < (3ull << 20) + (size_t)nsplit * (4ull << 20))
        nsplit >>= 1;
    const int ksplit = NN / nsplit;

    prep_kernel<<<dim3(128, 4), 256, 0, stream>>>(feats, W, ak, Bpack, Es, Fs, En, Fn);
    attn_kernel<<<dim3(128, nsplit), 256, 0, stream>>>(adj, Bpack, Es, Fs, En, Fn,
                                                       pacc, pden, ksplit);
    finalize_kernel<<<1024, 256, 0, stream>>>(pacc, pden, out, nsplit);
}